// Round 11
// baseline (126.852 us; speedup 1.0000x reference)
//
#include <hip/hip_runtime.h>
#include <hip/hip_bf16.h>
#include <stdint.h>

#define B_ 16
#define C_ 128
#define L_ 2048
#define LOG2E 1.4426950408889634f

typedef __attribute__((ext_vector_type(8))) short bf16x8;
typedef __attribute__((ext_vector_type(4))) float f32x4;
typedef __attribute__((ext_vector_type(16))) float f32x16;
typedef __attribute__((ext_vector_type(4))) unsigned int u32x4;

typedef __attribute__((address_space(3))) unsigned int lds_u32_t;
typedef const __attribute__((address_space(1))) unsigned int gbl_u32_t;

__device__ __forceinline__ void gload_lds16(const void* g, void* l) {
  // linear wave-uniform LDS dest (base + lane*16), per-lane global src
  __builtin_amdgcn_global_load_lds((gbl_u32_t*)g,
                                   (lds_u32_t*)(unsigned long long)l, 16, 0, 0);
}

__device__ __forceinline__ unsigned short f2bf(float x) {  // RNE f32->bf16
  union { float f; unsigned u; } v; v.f = x;
  unsigned u = v.u;
  u += 0x7fffu + ((u >> 16) & 1u);
  return (unsigned short)(u >> 16);
}

__device__ __forceinline__ unsigned pk2(float a, float b) {
  return (unsigned)f2bf(a) | ((unsigned)f2bf(b) << 16);
}

__device__ __forceinline__ unsigned cvtpk_bf16(float lo, float hi_) {
  unsigned r;
  asm("v_cvt_pk_bf16_f32 %0, %1, %2" : "=v"(r) : "v"(lo), "v"(hi_));
  return r;
}

__device__ __forceinline__ float max3f(float a, float b, float c) {
  float r;
  asm("v_max3_f32 %0, %1, %2, %3" : "=v"(r) : "v"(a), "v"(b), "v"(c));
  return r;
}

__device__ __forceinline__ f32x16 z16() {
  f32x16 v;
#pragma unroll
  for (int i = 0; i < 16; ++i) v[i] = 0.f;
  return v;
}

__device__ __forceinline__ float tmax16(const f32x16& v) {
  float m0 = max3f(v[0], v[1], v[2]);
  float m1 = max3f(v[3], v[4], v[5]);
  float m2_ = max3f(v[6], v[7], v[8]);
  float m3 = max3f(v[9], v[10], v[11]);
  float m4 = max3f(v[12], v[13], v[14]);
  float a = max3f(m0, m1, m2_);
  float b = max3f(m3, m4, v[15]);
  return fmaxf(a, b);
}

__device__ __forceinline__ float tsum16(const f32x16& v) {
  float a0 = v[0] + v[1],  a1 = v[2] + v[3];
  float a2 = v[4] + v[5],  a3 = v[6] + v[7];
  float a4 = v[8] + v[9],  a5 = v[10] + v[11];
  float a6 = v[12] + v[13], a7 = v[14] + v[15];
  float b0 = a0 + a1, b1 = a2 + a3, b2 = a4 + a5, b3 = a6 + a7;
  return (b0 + b1) + (b2 + b3);
}

// ---------------------------------------------------------------------------
// Projection: Q[b,l,o] = (sum_c x[b,c,l]*W1[o,c] + b1[o]) * log2(e)  (bf16,[B][L][C])
//             K same with W2/b2 (unscaled); V transposed Vt[b,o,l] ([B][C][L])
// ---------------------------------------------------------------------------
__global__ __launch_bounds__(256, 2) void proj_kernel(
    const float* __restrict__ x,
    const float* __restrict__ W1, const float* __restrict__ b1,
    const float* __restrict__ W2, const float* __restrict__ b2,
    const float* __restrict__ W3, const float* __restrict__ b3,
    unsigned short* __restrict__ Qo, unsigned short* __restrict__ Ko,
    unsigned short* __restrict__ Vt)
{
  __shared__ unsigned short Xt[64][136];   // [l_local][c], pad 136 breaks conflicts
  __shared__ unsigned short Wl[128][136];  // [o][c]

  const int b  = blockIdx.x & 15;
  const int lt = blockIdx.x >> 4;          // 0..31
  const int l0 = lt * 64;
  const int tid = threadIdx.x;
  const int w = tid >> 6, lane = tid & 63, li = lane & 15, lg = lane >> 4;

  // stage X tile: x[b][c][l0..l0+63] -> Xt[l][c] (bf16)
  for (int it = 0; it < 8; ++it) {
    int idx = tid + it * 256;              // 0..2047
    int c = idx >> 4, f4 = idx & 15;
    const float4 vv = *(const float4*)(x + (size_t)(b * C_ + c) * L_ + l0 + f4 * 4);
    Xt[f4 * 4 + 0][c] = f2bf(vv.x);
    Xt[f4 * 4 + 1][c] = f2bf(vv.y);
    Xt[f4 * 4 + 2][c] = f2bf(vv.z);
    Xt[f4 * 4 + 3][c] = f2bf(vv.w);
  }

  auto stageW = [&](const float* W) {
    for (int it = 0; it < 16; ++it) {
      int idx = tid + it * 256;            // 0..4095
      int o = idx >> 5, f4 = idx & 31;
      const float4 vv = *(const float4*)(W + (size_t)o * C_ + f4 * 4);
      unsigned short* p = &Wl[o][f4 * 4];
      p[0] = f2bf(vv.x); p[1] = f2bf(vv.y); p[2] = f2bf(vv.z); p[3] = f2bf(vv.w);
    }
  };

  // mode 0: write [B][L][C] (Q/K), scaled by sc. mode 1: write transposed Vt.
  auto computePhase = [&](const float* bias, unsigned short* Out, int mode, float sc) {
    f32x4 acc[8];
#pragma unroll
    for (int ni = 0; ni < 8; ++ni) acc[ni] = (f32x4){0.f, 0.f, 0.f, 0.f};
    bf16x8 af[4];
#pragma unroll
    for (int kk = 0; kk < 4; ++kk)
      af[kk] = *(const bf16x8*)&Xt[w * 16 + li][lg * 8 + kk * 32];
#pragma unroll
    for (int kk = 0; kk < 4; ++kk) {
#pragma unroll
      for (int ni = 0; ni < 8; ++ni) {
        bf16x8 bf = *(const bf16x8*)&Wl[ni * 16 + li][lg * 8 + kk * 32];
        acc[ni] = __builtin_amdgcn_mfma_f32_16x16x32_bf16(af[kk], bf, acc[ni], 0, 0, 0);
      }
    }
    if (mode == 0) {
#pragma unroll
      for (int ni = 0; ni < 8; ++ni) {
        float bv = bias[ni * 16 + li];
#pragma unroll
        for (int r = 0; r < 4; ++r) {
          int lrow = l0 + w * 16 + lg * 4 + r;
          Out[(size_t)(b * L_ + lrow) * C_ + ni * 16 + li] = f2bf((acc[ni][r] + bv) * sc);
        }
      }
    } else {
#pragma unroll
      for (int ni = 0; ni < 8; ++ni) {
        float bv = bias[ni * 16 + li];
        int o = ni * 16 + li;
        unsigned long long pw =
            (unsigned long long)pk2(acc[ni][0] + bv, acc[ni][1] + bv) |
            ((unsigned long long)pk2(acc[ni][2] + bv, acc[ni][3] + bv) << 32);
        *(unsigned long long*)(Out + (size_t)(b * C_ + o) * L_ + l0 + w * 16 + lg * 4) = pw;
      }
    }
  };

  stageW(W1);
  __syncthreads();
  computePhase(b1, Qo, 0, LOG2E);   // Q pre-scaled: scores land in log2-domain
  __syncthreads();
  stageW(W2);
  __syncthreads();
  computePhase(b2, Ko, 0, 1.0f);
  __syncthreads();
  stageW(W3);
  __syncthreads();
  computePhase(b3, Vt, 1, 1.0f);
}

// ---------------------------------------------------------------------------
// Flash attention, 32x32x16 MFMA. Block = (batch, 64 q-rows), 4 waves paired
// (qg, jh). OCCUPANCY round: single 32KB K+V buffer (no dbuf) -> 33KB LDS ->
// 4 blocks/CU = 4 waves/SIMD (launch_bounds(256,4), VGPR<=128). Stage latency
// is hidden by the other 3 resident blocks, not intra-block pipelining.
// Schedule per tile (trivially sound): stage(t) -> syncthreads -> compute(t)
// -> syncthreads. Cross-lane: __shfl_xor only (R5-8: inline-asm permlane unsafe).
// ---------------------------------------------------------------------------
__global__ __launch_bounds__(256, 4) void attn_kernel(
    const unsigned short* __restrict__ Q,
    const unsigned short* __restrict__ K,
    const unsigned short* __restrict__ Vt,
    float* __restrict__ out)
{
  __shared__ __align__(16) char smem[33792];  // K [0,16K), V [16K,32K), ml @32768

  const int b  = blockIdx.x & 15;               // batch -> XCD (L2-resident K/V)
  const int qt = blockIdx.x >> 4;               // 0..31
  const int tid = threadIdx.x;
  const int w = tid >> 6, lane = tid & 63;      // w: 0..3
  const int q32 = lane & 31, hi = lane >> 5;
  const int qg = (w >> 1) & 1, jh = w & 1;
  const int qrow = qt * 64 + qg * 32 + q32;
  const size_t bLC = (size_t)b * L_ * C_;

  // Q B-frags: lane holds Q[qrow][kt*16 + hi*8 .. +7]
  bf16x8 qf[8];
  {
    const unsigned short* qp = Q + bLC + (size_t)qrow * C_ + hi * 8;
#pragma unroll
    for (int kt = 0; kt < 8; ++kt) qf[kt] = *(const bf16x8*)(qp + kt * 16);
  }

  f32x16 oacc[4];
#pragma unroll
  for (int i = 0; i < 4; ++i) oacc[i] = z16();
  float m2 = -3e38f, lrun = 0.f;                // running max in log2 units

  // ---- hoisted LDS read offsets (constant per lane) ----
  const int krow = jh * 32 + q32;
  int kvo[8];
#pragma unroll
  for (int kt = 0; kt < 8; ++kt)
    kvo[kt] = (krow << 8) + ((kt * 32 + hi * 16) ^ ((krow & 15) << 4));
  int vvo[8];
#pragma unroll
  for (int kj = 0; kj < 2; ++kj)
#pragma unroll
    for (int ct = 0; ct < 4; ++ct) {
      int rowc = ct * 32 + q32;
      vvo[kj * 4 + ct] = 16384 + (rowc << 7) +
                         (((jh * 2 + kj) * 32 + hi * 16) ^ ((rowc & 7) << 4));
    }

  // ---- hoisted stage source offsets + loop-carried base (wave role: w<2 K, else V)
  int soff[8];
  const char* sp;
  int dbase, sadv;
  if (w < 2) {
    sp = (const char*)(K + bLC);
    dbase = w * 8192; sadv = 16384;            // K tiles: 16KB stride in global
#pragma unroll
    for (int i2 = 0; i2 < 8; ++i2) {
      int d = w * 8192 + i2 * 1024 + lane * 16;
      int row = d >> 8, cb = d & 255;
      soff[i2] = row * 256 + (cb ^ ((row & 15) << 4));
    }
  } else {
    sp = (const char*)(Vt + bLC);
    dbase = 16384 + (w - 2) * 8192; sadv = 128; // V tiles: 128B col advance
#pragma unroll
    for (int i2 = 0; i2 < 8; ++i2) {
      int d = (w - 2) * 8192 + i2 * 1024 + lane * 16;
      int rc = d >> 7, cv = d & 127;
      soff[i2] = rc * 4096 + (cv ^ ((rc & 7) << 4));
    }
  }

  for (int t = 0; t < 32; ++t) {
    // ---- stage tile t into the single buffer
#pragma unroll
    for (int i2 = 0; i2 < 8; ++i2)
      gload_lds16(sp + soff[i2], &smem[dbase + i2 * 1024]);
    sp += sadv;
    __syncthreads();                 // full drain: tile t resident block-wide

    // ---- QK^T: this wave's j-half; 8-deep MFMA chain
    f32x16 s = z16();
    __builtin_amdgcn_s_setprio(1);
#pragma unroll
    for (int kt = 0; kt < 8; ++kt) {
      bf16x8 kf = *(const bf16x8*)&smem[kvo[kt]];
      s = __builtin_amdgcn_mfma_f32_32x32x16_bf16(kf, qf[kt], s, 0, 0, 0);
    }
    __builtin_amdgcn_s_setprio(0);

    // ---- online softmax over this wave's 32 j (log2 domain, defer-max THR=8)
    float pm = tmax16(s);
    pm = fmaxf(pm, __shfl_xor(pm, 32));
    if (!__all(pm - m2 <= 8.f)) {
      float mn = fmaxf(m2, pm);
      float al = exp2f(m2 - mn);
      lrun *= al;
#pragma unroll
      for (int ct = 0; ct < 4; ++ct) oacc[ct] = oacc[ct] * al;
      m2 = mn;
    }
#pragma unroll
    for (int r = 0; r < 16; ++r) s[r] = exp2f(s[r] - m2);
    float ps = tsum16(s);
    ps += __shfl_xor(ps, 32);
    lrun += ps;

    // ---- P frags (proven shfl+select): j_local kj*16 + hi*8 + 0..7
    bf16x8 pf[2];
#pragma unroll
    for (int kj = 0; kj < 2; ++kj) {
      const int base = kj * 8;
      unsigned wl0 = cvtpk_bf16(s[base + 0], s[base + 1]);
      unsigned wl1 = cvtpk_bf16(s[base + 2], s[base + 3]);
      unsigned wh0 = cvtpk_bf16(s[base + 4], s[base + 5]);
      unsigned wh1 = cvtpk_bf16(s[base + 6], s[base + 7]);
      unsigned snd0 = hi ? wl0 : wh0;
      unsigned snd1 = hi ? wl1 : wh1;
      unsigned rcv0 = (unsigned)__shfl_xor((int)snd0, 32);
      unsigned rcv1 = (unsigned)__shfl_xor((int)snd1, 32);
      unsigned w0 = hi ? rcv0 : wl0;
      unsigned w1 = hi ? rcv1 : wl1;
      unsigned w2 = hi ? wh0 : rcv0;
      unsigned w3 = hi ? wh1 : rcv1;
      u32x4 pw = {w0, w1, w2, w3};
      pf[kj] = *reinterpret_cast<bf16x8*>(&pw);
    }

    // ---- PV: O^T[c, q] += Vt_tile[:, jh-half] * P
    __builtin_amdgcn_s_setprio(1);
#pragma unroll
    for (int kj = 0; kj < 2; ++kj)
#pragma unroll
      for (int ct = 0; ct < 4; ++ct) {
        bf16x8 vf = *(const bf16x8*)&smem[vvo[kj * 4 + ct]];
        oacc[ct] = __builtin_amdgcn_mfma_f32_32x32x16_bf16(vf, pf[kj], oacc[ct], 0, 0, 0);
      }
    __builtin_amdgcn_s_setprio(0);

    __syncthreads();                 // reads retired: buffer reusable next tile
  }

  // ---- pair combine: (qg, jh=0) merges (qg, jh=1)'s partial (m, l, O) exactly
  float* mlb = (float*)(smem + 32768);          // [4 waves][32 q][2]
  if (hi == 0) {
    mlb[(w * 32 + q32) * 2 + 0] = m2;
    mlb[(w * 32 + q32) * 2 + 1] = lrun;
  }
  __syncthreads();
  const float mB = mlb[((w ^ 1) * 32 + q32) * 2 + 0];
  const float lB = mlb[((w ^ 1) * 32 + q32) * 2 + 1];
  const float mstar = fmaxf(m2, mB);
  const float aown  = exp2f(m2 - mstar);
  float* scrb = (float*)smem + (size_t)(qg * 64 + lane) * 33;  // pad-33: conflict-free
  float* ob = out + (size_t)b * C_ * L_ + qrow;
  float inv = 0.f;
  if (jh == 0) {
    const float aB = exp2f(mB - mstar);
    inv = 1.0f / (lrun * aown + lB * aB);
  }
  __syncthreads();
  if (jh == 1) {
#pragma unroll
    for (int r = 0; r < 16; ++r) {
      scrb[r]      = oacc[0][r] * aown;
      scrb[16 + r] = oacc[1][r] * aown;
    }
  }
  __syncthreads();
  if (jh == 0) {
#pragma unroll
    for (int ct = 0; ct < 2; ++ct)
#pragma unroll
      for (int r = 0; r < 16; ++r) {
        float v = oacc[ct][r] * aown + scrb[ct * 16 + r];
        int c = ct * 32 + (r & 3) + 8 * (r >> 2) + 4 * hi;
        ob[(size_t)c * L_] = v * inv;
      }
  }
  __syncthreads();
  if (jh == 1) {
#pragma unroll
    for (int r = 0; r < 16; ++r) {
      scrb[r]      = oacc[2][r] * aown;
      scrb[16 + r] = oacc[3][r] * aown;
    }
  }
  __syncthreads();
  if (jh == 0) {
#pragma unroll
    for (int ct = 0; ct < 2; ++ct)
#pragma unroll
      for (int r = 0; r < 16; ++r) {
        float v = oacc[2 + ct][r] * aown + scrb[ct * 16 + r];
        int c = (2 + ct) * 32 + (r & 3) + 8 * (r >> 2) + 4 * hi;
        ob[(size_t)c * L_] = v * inv;
      }
  }
}

extern "C" void kernel_launch(void* const* d_in, const int* in_sizes, int n_in,
                              void* d_out, int out_size, void* d_ws, size_t ws_size,
                              hipStream_t stream) {
  (void)in_sizes; (void)n_in; (void)out_size; (void)ws_size;
  const float* x  = (const float*)d_in[0];
  const float* W1 = (const float*)d_in[1];
  const float* b1 = (const float*)d_in[2];
  const float* W2 = (const float*)d_in[3];
  const float* b2 = (const float*)d_in[4];
  const float* W3 = (const float*)d_in[5];
  const float* b3 = (const float*)d_in[6];

  unsigned short* Q  = (unsigned short*)d_ws;              // [B][L][C] bf16 (x log2e)
  unsigned short* K  = Q + (size_t)B_ * L_ * C_;           // [B][L][C] bf16
  unsigned short* Vt = K + (size_t)B_ * L_ * C_;           // [B][C][L] bf16

  proj_kernel<<<512, 256, 0, stream>>>(x, W1, b1, W2, b2, W3, b3, Q, K, Vt);
  attn_kernel<<<512, 256, 0, stream>>>(Q, K, Vt, (float*)d_out);
}